// Round 11
// baseline (117.120 us; speedup 1.0000x reference)
//
#include <hip/hip_runtime.h>
#include <hip/hip_cooperative_groups.h>

namespace cg = cooperative_groups;

#define SIGMA_C 1e-4f
#define EPS_C   1e-12f
#define GPT     4          // int4 groups per thread, 2 pairs per group -> 8 pairs/thread

struct V3 { float x, y, z; };
typedef float v2f __attribute__((ext_vector_type(2)));

__device__ __forceinline__ V3 v3sub(V3 a, V3 b) { return {a.x - b.x, a.y - b.y, a.z - b.z}; }
__device__ __forceinline__ float v3dot(V3 a, V3 b) { return a.x * b.x + a.y * b.y + a.z * b.z; }
__device__ __forceinline__ V3 v3cross(V3 a, V3 b) {
    return {a.y * b.z - a.z * b.y,
            a.z * b.x - a.x * b.z,
            a.x * b.y - a.y * b.x};
}
__device__ __forceinline__ int imax0(int x) { return x > 0 ? x : 0; }

__device__ __forceinline__ void tri_frame(const V3 v[3], V3& c, V3& n, float& r) {
    const float third = 1.0f / 3.0f;
    c.x = (v[0].x + v[1].x + v[2].x) * third;
    c.y = (v[0].y + v[1].y + v[2].y) * third;
    c.z = (v[0].z + v[1].z + v[2].z) * third;
    V3 e1 = v3sub(v[1], v[0]);
    V3 e2 = v3sub(v[2], v[0]);
    n = v3cross(e1, e2);
    float nn = sqrtf(v3dot(n, n));
    float inv = 1.0f / fmaxf(nn, EPS_C);
    n.x *= inv; n.y *= inv; n.z *= inv;
    V3 d0 = v3sub(v[0], c), d1 = v3sub(v[1], c), d2 = v3sub(v[2], c);
    float m = fmaxf(fmaxf(v3dot(d0, d0), v3dot(d1, d1)), v3dot(d2, d2));
    r = sqrtf(m);
}

__device__ __forceinline__ float cone_psi2(const V3 p[3], V3 c, V3 n, float r) {
    float inv_r = 1.0f / fmaxf(r, EPS_C);
    float s = 0.0f;
#pragma unroll
    for (int i = 0; i < 3; ++i) {
        V3 u = v3sub(p[i], c);
        float h = v3dot(u, n);
        V3 w = {u.x - h * n.x, u.y - h * n.y, u.z - h * n.z};
        float rho = sqrtf(v3dot(w, w));
        float radial = fmaxf(1.0f - rho * inv_r, 0.0f);
        float axial = fmaxf(SIGMA_C - h, 0.0f);   // PENALIZE_OUTSIDE = True
        float psi = radial * axial;
        s += psi * psi;
    }
    return s;
}

// fp8 e4m3 record: 16 bytes, one dwordx4 load.
// b0..b8 = v0 v1 v2 (xyz each), b9..b11 = c, b12..b14 = n, b15 = r
struct RecF { V3 p0, p1, p2, c, n; float r; };

__device__ __forceinline__ void decode_rec8(float4 q, RecF& o) {
    int4 d = *(int4*)&q;
    v2f t0 = __builtin_amdgcn_cvt_pk_f32_fp8(d.x, false);
    v2f t1 = __builtin_amdgcn_cvt_pk_f32_fp8(d.x, true);
    v2f t2 = __builtin_amdgcn_cvt_pk_f32_fp8(d.y, false);
    v2f t3 = __builtin_amdgcn_cvt_pk_f32_fp8(d.y, true);
    v2f t4 = __builtin_amdgcn_cvt_pk_f32_fp8(d.z, false);
    v2f t5 = __builtin_amdgcn_cvt_pk_f32_fp8(d.z, true);
    v2f t6 = __builtin_amdgcn_cvt_pk_f32_fp8(d.w, false);
    v2f t7 = __builtin_amdgcn_cvt_pk_f32_fp8(d.w, true);
    o.p0 = {t0.x, t0.y, t1.x};
    o.p1 = {t1.y, t2.x, t2.y};
    o.p2 = {t3.x, t3.y, t4.x};
    o.c  = {t4.y, t5.x, t5.y};
    o.n  = {t6.x, t6.y, t7.x};
    o.r  = t7.y;
}

__device__ __forceinline__ float compute_pair8(float4 R, float4 I, float w) {
    RecF rr, ii;
    decode_rec8(R, rr);
    decode_rec8(I, ii);
    V3 rp[3] = {rr.p0, rr.p1, rr.p2};
    V3 ip[3] = {ii.p0, ii.p1, ii.p2};
    return w * (cone_psi2(ip, rr.c, rr.n, rr.r) + cone_psi2(rp, ii.c, ii.n, ii.r));
}

__device__ __forceinline__ void gather_group8(const float4* __restrict__ tb, int4 q,
                                              float4 G[4], float w[2]) {
    w[0] = ((q.x | q.y) >= 0) ? 1.0f : 0.0f;
    w[1] = ((q.z | q.w) >= 0) ? 1.0f : 0.0f;
    G[0] = tb[imax0(q.x)];
    G[1] = tb[imax0(q.y)];
    G[2] = tb[imax0(q.z)];
    G[3] = tb[imax0(q.w)];
}
__device__ __forceinline__ float compute_group8(const float4 G[4], const float w[2]) {
    return compute_pair8(G[0], G[1], w[0]) + compute_pair8(G[2], G[3], w[1]);
}

// ---------------- fused cooperative kernel ----------------
// phase A: build fp8 table slice  | grid.sync | phase C: round-10 pair loop
__global__ void __launch_bounds__(256, 4)
fused_f8(const float* __restrict__ verts,   // [B,V,3]
         const int*   __restrict__ faces,   // [F,3]
         const int4*  __restrict__ coll4,   // [B*C4]
         float4* __restrict__ table,        // [B*F]
         float* __restrict__ out,           // [B]
         int V, int F, int C4, int B, int FPB) {
    const int b = blockIdx.x % B;                 // batch -> XCD pinning (both phases)
    const int chunk = blockIdx.x / B;

    // ---- phase A ----
    if (blockIdx.x == 0 && threadIdx.x < (unsigned)B)
        out[threadIdx.x] = 0.0f;

    {
        const float* vb = verts + (size_t)b * (size_t)V * 3u;
        const int fbeg = chunk * FPB;
        const int fend = min(fbeg + FPB, F);
        for (int f = fbeg + (int)threadIdx.x; f < fend; f += 256) {
            int i0 = faces[3 * f + 0];
            int i1 = faces[3 * f + 1];
            int i2 = faces[3 * f + 2];
            V3 v[3];
            v[0] = {vb[3 * i0 + 0], vb[3 * i0 + 1], vb[3 * i0 + 2]};
            v[1] = {vb[3 * i1 + 0], vb[3 * i1 + 1], vb[3 * i1 + 2]};
            v[2] = {vb[3 * i2 + 0], vb[3 * i2 + 1], vb[3 * i2 + 2]};
            V3 c, n; float r;
            tri_frame(v, c, n, r);
            int d0 = 0, d1 = 0, d2 = 0, d3 = 0;
            d0 = __builtin_amdgcn_cvt_pk_fp8_f32(v[0].x, v[0].y, d0, false);
            d0 = __builtin_amdgcn_cvt_pk_fp8_f32(v[0].z, v[1].x, d0, true);
            d1 = __builtin_amdgcn_cvt_pk_fp8_f32(v[1].y, v[1].z, d1, false);
            d1 = __builtin_amdgcn_cvt_pk_fp8_f32(v[2].x, v[2].y, d1, true);
            d2 = __builtin_amdgcn_cvt_pk_fp8_f32(v[2].z, c.x, d2, false);
            d2 = __builtin_amdgcn_cvt_pk_fp8_f32(c.y, c.z, d2, true);
            d3 = __builtin_amdgcn_cvt_pk_fp8_f32(n.x, n.y, d3, false);
            d3 = __builtin_amdgcn_cvt_pk_fp8_f32(n.z, r, d3, true);
            int4 rec = {d0, d1, d2, d3};
            table[(size_t)b * F + f] = *(float4*)&rec;
        }
    }

    cg::this_grid().sync();   // device-scope fence: table visible across XCDs

    // ---- phase C: ping-pong pair loop (round-10 structure, unchanged) ----
    const int4* cb = coll4 + (size_t)b * C4;
    const float4* tb = table + (size_t)b * (size_t)F;
    const int base = chunk * (256 * GPT) + (int)threadIdx.x;

    float acc = 0.0f;
    float4 GA[4], GB[4];
    float wA[2], wB[2];
    int4 q_even, q_odd;
    {
        int g0 = base, g1 = base + 256;
        q_even = (g0 < C4) ? cb[g0] : make_int4(-1, -1, -1, -1);
        q_odd  = (g1 < C4) ? cb[g1] : make_int4(-1, -1, -1, -1);
        gather_group8(tb, q_even, GA, wA);
    }
#pragma unroll
    for (int i = 0; i < GPT; ++i) {
        if ((i & 1) == 0) {
            if (i + 2 < GPT) {
                int g = base + (i + 2) * 256;
                q_even = (g < C4) ? cb[g] : make_int4(-1, -1, -1, -1);
            }
            if (i + 1 < GPT) gather_group8(tb, q_odd, GB, wB);
            acc += compute_group8(GA, wA);
        } else {
            if (i + 2 < GPT) {
                int g = base + (i + 2) * 256;
                q_odd = (g < C4) ? cb[g] : make_int4(-1, -1, -1, -1);
            }
            if (i + 1 < GPT) gather_group8(tb, q_even, GA, wA);
            acc += compute_group8(GB, wB);
        }
    }

#pragma unroll
    for (int off = 32; off > 0; off >>= 1)
        acc += __shfl_down(acc, off, 64);

    __shared__ float red[4];
    int lane = threadIdx.x & 63;
    int wid  = threadIdx.x >> 6;
    if (lane == 0) red[wid] = acc;
    __syncthreads();
    if (threadIdx.x == 0) {
        float s = red[0] + red[1] + red[2] + red[3];
        atomicAdd(&out[b], s);
    }
}

// ---------------- fallback A: round-10 two-kernel path ----------------
__global__ void precompute_tri_8(const float* __restrict__ verts,
                                 const int*   __restrict__ faces,
                                 float4* __restrict__ table,
                                 float* __restrict__ out,
                                 int V, int F, int B) {
    if (blockIdx.x == 0 && threadIdx.x < (unsigned)B)
        out[threadIdx.x] = 0.0f;

    const int b = blockIdx.x % B;
    const int chunk = blockIdx.x / B;
    const int f = chunk * blockDim.x + threadIdx.x;
    if (f >= F) return;

    const float* vb = verts + (size_t)b * (size_t)V * 3u;
    int i0 = faces[3 * f + 0];
    int i1 = faces[3 * f + 1];
    int i2 = faces[3 * f + 2];
    V3 v[3];
    v[0] = {vb[3 * i0 + 0], vb[3 * i0 + 1], vb[3 * i0 + 2]};
    v[1] = {vb[3 * i1 + 0], vb[3 * i1 + 1], vb[3 * i1 + 2]};
    v[2] = {vb[3 * i2 + 0], vb[3 * i2 + 1], vb[3 * i2 + 2]};
    V3 c, n; float r;
    tri_frame(v, c, n, r);
    int d0 = 0, d1 = 0, d2 = 0, d3 = 0;
    d0 = __builtin_amdgcn_cvt_pk_fp8_f32(v[0].x, v[0].y, d0, false);
    d0 = __builtin_amdgcn_cvt_pk_fp8_f32(v[0].z, v[1].x, d0, true);
    d1 = __builtin_amdgcn_cvt_pk_fp8_f32(v[1].y, v[1].z, d1, false);
    d1 = __builtin_amdgcn_cvt_pk_fp8_f32(v[2].x, v[2].y, d1, true);
    d2 = __builtin_amdgcn_cvt_pk_fp8_f32(v[2].z, c.x, d2, false);
    d2 = __builtin_amdgcn_cvt_pk_fp8_f32(c.y, c.z, d2, true);
    d3 = __builtin_amdgcn_cvt_pk_fp8_f32(n.x, n.y, d3, false);
    d3 = __builtin_amdgcn_cvt_pk_fp8_f32(n.z, r, d3, true);
    int4 rec = {d0, d1, d2, d3};
    table[(size_t)b * F + f] = *(float4*)&rec;
}

__global__ void __launch_bounds__(256)
pair_kernel_f8(const float4* __restrict__ table,
               const int4*  __restrict__ coll4,
               float* __restrict__ out,
               int F, int C4, int B) {
    const int b = blockIdx.x % B;
    const int chunk = blockIdx.x / B;
    const int4* cb = coll4 + (size_t)b * C4;
    const float4* tb = table + (size_t)b * (size_t)F;
    const int base = chunk * (256 * GPT) + threadIdx.x;

    float acc = 0.0f;
    float4 GA[4], GB[4];
    float wA[2], wB[2];
    int4 q_even, q_odd;
    {
        int g0 = base, g1 = base + 256;
        q_even = (g0 < C4) ? cb[g0] : make_int4(-1, -1, -1, -1);
        q_odd  = (g1 < C4) ? cb[g1] : make_int4(-1, -1, -1, -1);
        gather_group8(tb, q_even, GA, wA);
    }
#pragma unroll
    for (int i = 0; i < GPT; ++i) {
        if ((i & 1) == 0) {
            if (i + 2 < GPT) {
                int g = base + (i + 2) * 256;
                q_even = (g < C4) ? cb[g] : make_int4(-1, -1, -1, -1);
            }
            if (i + 1 < GPT) gather_group8(tb, q_odd, GB, wB);
            acc += compute_group8(GA, wA);
        } else {
            if (i + 2 < GPT) {
                int g = base + (i + 2) * 256;
                q_odd = (g < C4) ? cb[g] : make_int4(-1, -1, -1, -1);
            }
            if (i + 1 < GPT) gather_group8(tb, q_even, GA, wA);
            acc += compute_group8(GB, wB);
        }
    }

#pragma unroll
    for (int off = 32; off > 0; off >>= 1)
        acc += __shfl_down(acc, off, 64);

    __shared__ float red[4];
    int lane = threadIdx.x & 63;
    int wid  = threadIdx.x >> 6;
    if (lane == 0) red[wid] = acc;
    __syncthreads();
    if (threadIdx.x == 0) {
        float s = red[0] + red[1] + red[2] + red[3];
        atomicAdd(&out[b], s);
    }
}

// ---------------- fallback B: direct gather (fp32 exact) ----------------
__global__ void interp_zero(float* out, int n) {
    int i = blockIdx.x * blockDim.x + threadIdx.x;
    if (i < n) out[i] = 0.0f;
}
__global__ void pair_kernel_gather(const float* __restrict__ verts,
                                   const int*   __restrict__ faces,
                                   const int2*  __restrict__ coll,
                                   float* __restrict__ out, int V, int C) {
    const int b = blockIdx.y;
    const float* vb = verts + (size_t)b * (size_t)V * 3u;
    const int2* cb = coll + (size_t)b * (size_t)C;
    float acc = 0.0f;
    const int stride = gridDim.x * blockDim.x;
    for (int c = blockIdx.x * blockDim.x + threadIdx.x; c < C; c += stride) {
        int2 idx = cb[c];
        if ((idx.x | idx.y) >= 0) {
            const int* fr = faces + 3 * idx.x;
            const int* fi = faces + 3 * idx.y;
            V3 tr[3], ti[3];
#pragma unroll
            for (int j = 0; j < 3; ++j) {
                int vr = fr[j];
                tr[j] = {vb[3 * vr + 0], vb[3 * vr + 1], vb[3 * vr + 2]};
                int vi = fi[j];
                ti[j] = {vb[3 * vi + 0], vb[3 * vi + 1], vb[3 * vi + 2]};
            }
            V3 rc, rn; float rr;
            tri_frame(tr, rc, rn, rr);
            V3 ic, in_; float ir;
            tri_frame(ti, ic, in_, ir);
            acc += cone_psi2(ti, rc, rn, rr);
            acc += cone_psi2(tr, ic, in_, ir);
        }
    }
#pragma unroll
    for (int off = 32; off > 0; off >>= 1)
        acc += __shfl_down(acc, off, 64);
    __shared__ float red[16];
    int lane = threadIdx.x & 63, wid = threadIdx.x >> 6;
    if (lane == 0) red[wid] = acc;
    __syncthreads();
    if (threadIdx.x == 0) {
        float s = 0.0f;
        int nw = blockDim.x >> 6;
        for (int i = 0; i < nw; ++i) s += red[i];
        atomicAdd(&out[b], s);
    }
}

extern "C" void kernel_launch(void* const* d_in, const int* in_sizes, int n_in,
                              void* d_out, int out_size, void* d_ws, size_t ws_size,
                              hipStream_t stream) {
    const float* verts = (const float*)d_in[0];
    const int*   faces = (const int*)d_in[1];
    float* out = (float*)d_out;

    const int B = out_size;                       // 8
    const int V = in_sizes[0] / (3 * B);          // 10475
    const int F = in_sizes[1] / 3;                // 20908
    const int C = in_sizes[2] / (2 * B);          // 262144

    const size_t table_bytes = (size_t)B * (size_t)F * 16u;
    const int per_block_pairs = 256 * GPT * 2;    // 2048 pairs per block

    if (ws_size >= table_bytes && (C % per_block_pairs) == 0) {
        float4* table = (float4*)d_ws;
        const int4* coll4 = (const int4*)d_in[2];
        int C4 = C / 2;
        int chunks = C / per_block_pairs;         // per batch: 128
        int grid = chunks * B;                    // 1024 = 4 blocks/CU (co-resident)
        int FPB = (F + chunks - 1) / chunks;      // faces per chunk

        void* tblv = (void*)table;
        void* args[] = {(void*)&verts, (void*)&faces, (void*)&coll4, (void*)&tblv,
                        (void*)&out, (void*)&V, (void*)&F, (void*)&C4, (void*)&B, (void*)&FPB};
        hipError_t err = hipLaunchCooperativeKernel(
            (const void*)fused_f8, dim3(grid), dim3(256), args, 0, stream);
        if (err == hipSuccess) return;

        // cooperative launch unavailable -> two-kernel path
        const int pchunks = (F + 255) / 256;
        precompute_tri_8<<<dim3(pchunks * B), dim3(256), 0, stream>>>(
            verts, faces, table, out, V, F, B);
        pair_kernel_f8<<<dim3(chunks * B), dim3(256), 0, stream>>>(
            table, coll4, out, F, C4, B);
    } else {
        interp_zero<<<1, 64, 0, stream>>>(out, B);
        pair_kernel_gather<<<dim3(256, B), dim3(256), 0, stream>>>(
            verts, faces, (const int2*)d_in[2], out, V, C);
    }
}

// Round 13
// 41.207 us; speedup vs baseline: 2.8423x; 2.8423x over previous
//
#include <hip/hip_runtime.h>

#define SIGMA_C 1e-4f
#define EPS_C   1e-12f

struct V3 { float x, y, z; };
typedef float v2f __attribute__((ext_vector_type(2)));
typedef int   v4i __attribute__((ext_vector_type(4)));

__device__ __forceinline__ V3 v3sub(V3 a, V3 b) { return {a.x - b.x, a.y - b.y, a.z - b.z}; }
__device__ __forceinline__ float v3dot(V3 a, V3 b) { return a.x * b.x + a.y * b.y + a.z * b.z; }
__device__ __forceinline__ V3 v3cross(V3 a, V3 b) {
    return {a.y * b.z - a.z * b.y,
            a.z * b.x - a.x * b.z,
            a.x * b.y - a.y * b.x};
}
__device__ __forceinline__ int imax0(int x) { return x > 0 ? x : 0; }

__device__ __forceinline__ void tri_frame(const V3 v[3], V3& c, V3& n, float& r) {
    const float third = 1.0f / 3.0f;
    c.x = (v[0].x + v[1].x + v[2].x) * third;
    c.y = (v[0].y + v[1].y + v[2].y) * third;
    c.z = (v[0].z + v[1].z + v[2].z) * third;
    V3 e1 = v3sub(v[1], v[0]);
    V3 e2 = v3sub(v[2], v[0]);
    n = v3cross(e1, e2);
    float nn = sqrtf(v3dot(n, n));
    float inv = 1.0f / fmaxf(nn, EPS_C);
    n.x *= inv; n.y *= inv; n.z *= inv;
    V3 d0 = v3sub(v[0], c), d1 = v3sub(v[1], c), d2 = v3sub(v[2], c);
    float m = fmaxf(fmaxf(v3dot(d0, d0), v3dot(d1, d1)), v3dot(d2, d2));
    r = sqrtf(m);
}

__device__ __forceinline__ float cone_psi2(const V3 p[3], V3 c, V3 n, float r) {
    float inv_r = 1.0f / fmaxf(r, EPS_C);
    float s = 0.0f;
#pragma unroll
    for (int i = 0; i < 3; ++i) {
        V3 u = v3sub(p[i], c);
        float h = v3dot(u, n);
        V3 w = {u.x - h * n.x, u.y - h * n.y, u.z - h * n.z};
        float rho = sqrtf(v3dot(w, w));
        float radial = fmaxf(1.0f - rho * inv_r, 0.0f);
        float axial = fmaxf(SIGMA_C - h, 0.0f);   // PENALIZE_OUTSIDE = True
        float psi = radial * axial;
        s += psi * psi;
    }
    return s;
}

// fp8 e4m3 record: 16 bytes, one dwordx4 load.
// b0..b8 = v0 v1 v2 (xyz each), b9..b11 = c, b12..b14 = n, b15 = r
struct RecF { V3 p0, p1, p2, c, n; float r; };

__device__ __forceinline__ void decode_rec8(float4 q, RecF& o) {
    int4 d = *(int4*)&q;
    v2f t0 = __builtin_amdgcn_cvt_pk_f32_fp8(d.x, false);
    v2f t1 = __builtin_amdgcn_cvt_pk_f32_fp8(d.x, true);
    v2f t2 = __builtin_amdgcn_cvt_pk_f32_fp8(d.y, false);
    v2f t3 = __builtin_amdgcn_cvt_pk_f32_fp8(d.y, true);
    v2f t4 = __builtin_amdgcn_cvt_pk_f32_fp8(d.z, false);
    v2f t5 = __builtin_amdgcn_cvt_pk_f32_fp8(d.z, true);
    v2f t6 = __builtin_amdgcn_cvt_pk_f32_fp8(d.w, false);
    v2f t7 = __builtin_amdgcn_cvt_pk_f32_fp8(d.w, true);
    o.p0 = {t0.x, t0.y, t1.x};
    o.p1 = {t1.y, t2.x, t2.y};
    o.p2 = {t3.x, t3.y, t4.x};
    o.c  = {t4.y, t5.x, t5.y};
    o.n  = {t6.x, t6.y, t7.x};
    o.r  = t7.y;
}

__device__ __forceinline__ float compute_pair8(float4 R, float4 I, float w) {
    RecF rr, ii;
    decode_rec8(R, rr);
    decode_rec8(I, ii);
    V3 rp[3] = {rr.p0, rr.p1, rr.p2};
    V3 ip[3] = {ii.p0, ii.p1, ii.p2};
    return w * (cone_psi2(ip, rr.c, rr.n, rr.r) + cone_psi2(rp, ii.c, ii.n, ii.r));
}

__device__ __forceinline__ void gather_group8(const float4* __restrict__ tb, int4 q,
                                              float4 G[4], float w[2]) {
    w[0] = ((q.x | q.y) >= 0) ? 1.0f : 0.0f;
    w[1] = ((q.z | q.w) >= 0) ? 1.0f : 0.0f;
    G[0] = tb[imax0(q.x)];
    G[1] = tb[imax0(q.y)];
    G[2] = tb[imax0(q.z)];
    G[3] = tb[imax0(q.w)];
}
__device__ __forceinline__ float compute_group8(const float4 G[4], const float w[2]) {
    return compute_pair8(G[0], G[1], w[0]) + compute_pair8(G[2], G[3], w[1]);
}

// nontemporal int4 load via clang native vector type
__device__ __forceinline__ int4 nt_load_i4(const int4* p) {
    v4i v = __builtin_nontemporal_load((const v4i*)p);
    return make_int4(v.x, v.y, v.z, v.w);
}

// ---------------- phase 1: per-(batch,face) 16-B fp8 record ----------------
__global__ void precompute_tri_8(const float* __restrict__ verts,  // [B,V,3]
                                 const int*   __restrict__ faces,  // [F,3]
                                 float4* __restrict__ table,       // [B*F]
                                 float* __restrict__ out,          // [B]
                                 int V, int F, int B) {
    if (blockIdx.x == 0 && threadIdx.x < (unsigned)B)
        out[threadIdx.x] = 0.0f;

    const int b = blockIdx.x % B;      // batch -> XCD co-location with pair kernel
    const int chunk = blockIdx.x / B;
    const int f = chunk * blockDim.x + threadIdx.x;
    if (f >= F) return;

    const float* vb = verts + (size_t)b * (size_t)V * 3u;
    int i0 = faces[3 * f + 0];
    int i1 = faces[3 * f + 1];
    int i2 = faces[3 * f + 2];
    V3 v[3];
    v[0] = {vb[3 * i0 + 0], vb[3 * i0 + 1], vb[3 * i0 + 2]};
    v[1] = {vb[3 * i1 + 0], vb[3 * i1 + 1], vb[3 * i1 + 2]};
    v[2] = {vb[3 * i2 + 0], vb[3 * i2 + 1], vb[3 * i2 + 2]};
    V3 c, n; float r;
    tri_frame(v, c, n, r);
    int d0 = 0, d1 = 0, d2 = 0, d3 = 0;
    d0 = __builtin_amdgcn_cvt_pk_fp8_f32(v[0].x, v[0].y, d0, false);
    d0 = __builtin_amdgcn_cvt_pk_fp8_f32(v[0].z, v[1].x, d0, true);
    d1 = __builtin_amdgcn_cvt_pk_fp8_f32(v[1].y, v[1].z, d1, false);
    d1 = __builtin_amdgcn_cvt_pk_fp8_f32(v[2].x, v[2].y, d1, true);
    d2 = __builtin_amdgcn_cvt_pk_fp8_f32(v[2].z, c.x, d2, false);
    d2 = __builtin_amdgcn_cvt_pk_fp8_f32(c.y, c.z, d2, true);
    d3 = __builtin_amdgcn_cvt_pk_fp8_f32(n.x, n.y, d3, false);
    d3 = __builtin_amdgcn_cvt_pk_fp8_f32(n.z, r, d3, true);
    int4 rec = {d0, d1, d2, d3};
    table[(size_t)b * F + f] = *(float4*)&rec;
}

// ---------------- phase 2: depth-2 ping-pong, GPT=2, full occupancy ----------------
// grid = 2048 blocks = 8 blocks/CU -> 32 waves/CU (hardware max TLP)
__global__ void __launch_bounds__(256)
pair_kernel_f8(const float4* __restrict__ table,  // [B*F]
               const int4*  __restrict__ coll4,   // [B*C4]
               float* __restrict__ out,           // [B]
               int F, int C4, int B) {
    const int b = blockIdx.x % B;                 // batch -> XCD pinning
    const int chunk = blockIdx.x / B;
    const int4* cb = coll4 + (size_t)b * C4;
    const float4* tb = table + (size_t)b * (size_t)F;
    const int base = chunk * (256 * 2) + (int)threadIdx.x;

    // nontemporal: coll is streamed once, don't evict the hot table from L2
    int g0 = base, g1 = base + 256;
    int4 q_even = (g0 < C4) ? nt_load_i4(cb + g0) : make_int4(-1, -1, -1, -1);
    int4 q_odd  = (g1 < C4) ? nt_load_i4(cb + g1) : make_int4(-1, -1, -1, -1);

    float4 GA[4], GB[4];
    float wA[2], wB[2];

    gather_group8(tb, q_even, GA, wA);     // group 0 in flight
    gather_group8(tb, q_odd,  GB, wB);     // group 1 in flight (overlaps compute of 0)

    float acc = compute_group8(GA, wA);
    acc += compute_group8(GB, wB);

    // wave (64) shuffle reduction
#pragma unroll
    for (int off = 32; off > 0; off >>= 1)
        acc += __shfl_down(acc, off, 64);

    __shared__ float red[4];
    int lane = threadIdx.x & 63;
    int wid  = threadIdx.x >> 6;
    if (lane == 0) red[wid] = acc;
    __syncthreads();
    if (threadIdx.x == 0) {
        float s = red[0] + red[1] + red[2] + red[3];
        atomicAdd(&out[b], s);
    }
}

// ---------------- fallback: direct gather (fp32 exact) ----------------
__global__ void interp_zero(float* out, int n) {
    int i = blockIdx.x * blockDim.x + threadIdx.x;
    if (i < n) out[i] = 0.0f;
}
__global__ void pair_kernel_gather(const float* __restrict__ verts,
                                   const int*   __restrict__ faces,
                                   const int2*  __restrict__ coll,
                                   float* __restrict__ out, int V, int C) {
    const int b = blockIdx.y;
    const float* vb = verts + (size_t)b * (size_t)V * 3u;
    const int2* cb = coll + (size_t)b * (size_t)C;
    float acc = 0.0f;
    const int stride = gridDim.x * blockDim.x;
    for (int c = blockIdx.x * blockDim.x + threadIdx.x; c < C; c += stride) {
        int2 idx = cb[c];
        if ((idx.x | idx.y) >= 0) {
            const int* fr = faces + 3 * idx.x;
            const int* fi = faces + 3 * idx.y;
            V3 tr[3], ti[3];
#pragma unroll
            for (int j = 0; j < 3; ++j) {
                int vr = fr[j];
                tr[j] = {vb[3 * vr + 0], vb[3 * vr + 1], vb[3 * vr + 2]};
                int vi = fi[j];
                ti[j] = {vb[3 * vi + 0], vb[3 * vi + 1], vb[3 * vi + 2]};
            }
            V3 rc, rn; float rr;
            tri_frame(tr, rc, rn, rr);
            V3 ic, in_; float ir;
            tri_frame(ti, ic, in_, ir);
            acc += cone_psi2(ti, rc, rn, rr);
            acc += cone_psi2(tr, ic, in_, ir);
        }
    }
#pragma unroll
    for (int off = 32; off > 0; off >>= 1)
        acc += __shfl_down(acc, off, 64);
    __shared__ float red[16];
    int lane = threadIdx.x & 63, wid = threadIdx.x >> 6;
    if (lane == 0) red[wid] = acc;
    __syncthreads();
    if (threadIdx.x == 0) {
        float s = 0.0f;
        int nw = blockDim.x >> 6;
        for (int i = 0; i < nw; ++i) s += red[i];
        atomicAdd(&out[b], s);
    }
}

extern "C" void kernel_launch(void* const* d_in, const int* in_sizes, int n_in,
                              void* d_out, int out_size, void* d_ws, size_t ws_size,
                              hipStream_t stream) {
    const float* verts = (const float*)d_in[0];
    const int*   faces = (const int*)d_in[1];
    float* out = (float*)d_out;

    const int B = out_size;                       // 8
    const int V = in_sizes[0] / (3 * B);          // 10475
    const int F = in_sizes[1] / 3;                // 20908
    const int C = in_sizes[2] / (2 * B);          // 262144

    const size_t table_bytes = (size_t)B * (size_t)F * 16u;
    const int per_block_pairs = 256 * 2 * 2;      // 1024 pairs per block

    if (ws_size >= table_bytes && (C % per_block_pairs) == 0) {
        float4* table = (float4*)d_ws;
        const int4* coll4 = (const int4*)d_in[2];
        const int C4 = C / 2;

        const int pchunks = (F + 255) / 256;
        precompute_tri_8<<<dim3(pchunks * B), dim3(256), 0, stream>>>(
            verts, faces, table, out, V, F, B);

        const int chunks = C / per_block_pairs;   // per batch: 256
        pair_kernel_f8<<<dim3(chunks * B), dim3(256), 0, stream>>>(
            table, coll4, out, F, C4, B);
    } else {
        interp_zero<<<1, 64, 0, stream>>>(out, B);
        pair_kernel_gather<<<dim3(256, B), dim3(256), 0, stream>>>(
            verts, faces, (const int2*)d_in[2], out, V, C);
    }
}

// Round 14
// 31.906 us; speedup vs baseline: 3.6708x; 1.2915x over previous
//
#include <hip/hip_runtime.h>

#define SIGMA_C 1e-4f
#define EPS_C   1e-12f

struct V3 { float x, y, z; };
typedef float v2f __attribute__((ext_vector_type(2)));

__device__ __forceinline__ V3 v3sub(V3 a, V3 b) { return {a.x - b.x, a.y - b.y, a.z - b.z}; }
__device__ __forceinline__ float v3dot(V3 a, V3 b) { return a.x * b.x + a.y * b.y + a.z * b.z; }
__device__ __forceinline__ V3 v3cross(V3 a, V3 b) {
    return {a.y * b.z - a.z * b.y,
            a.z * b.x - a.x * b.z,
            a.x * b.y - a.y * b.x};
}
__device__ __forceinline__ int imax0(int x) { return x > 0 ? x : 0; }

__device__ __forceinline__ void tri_frame(const V3 v[3], V3& c, V3& n, float& r) {
    const float third = 1.0f / 3.0f;
    c.x = (v[0].x + v[1].x + v[2].x) * third;
    c.y = (v[0].y + v[1].y + v[2].y) * third;
    c.z = (v[0].z + v[1].z + v[2].z) * third;
    V3 e1 = v3sub(v[1], v[0]);
    V3 e2 = v3sub(v[2], v[0]);
    n = v3cross(e1, e2);
    float nn = sqrtf(v3dot(n, n));
    float inv = 1.0f / fmaxf(nn, EPS_C);
    n.x *= inv; n.y *= inv; n.z *= inv;
    V3 d0 = v3sub(v[0], c), d1 = v3sub(v[1], c), d2 = v3sub(v[2], c);
    float m = fmaxf(fmaxf(v3dot(d0, d0), v3dot(d1, d1)), v3dot(d2, d2));
    r = sqrtf(m);
}

__device__ __forceinline__ float cone_psi2(const V3 p[3], V3 c, V3 n, float r) {
    float inv_r = 1.0f / fmaxf(r, EPS_C);
    float s = 0.0f;
#pragma unroll
    for (int i = 0; i < 3; ++i) {
        V3 u = v3sub(p[i], c);
        float h = v3dot(u, n);
        V3 w = {u.x - h * n.x, u.y - h * n.y, u.z - h * n.z};
        float rho = sqrtf(v3dot(w, w));
        float radial = fmaxf(1.0f - rho * inv_r, 0.0f);
        float axial = fmaxf(SIGMA_C - h, 0.0f);   // PENALIZE_OUTSIDE = True
        float psi = radial * axial;
        s += psi * psi;
    }
    return s;
}

// fp8 e4m3 record: 16 bytes, one dwordx4 load.
// b0..b8 = v0 v1 v2 (xyz each), b9..b11 = c, b12..b14 = n, b15 = r
struct RecF { V3 p0, p1, p2, c, n; float r; };

__device__ __forceinline__ void decode_rec8(float4 q, RecF& o) {
    int4 d = *(int4*)&q;
    v2f t0 = __builtin_amdgcn_cvt_pk_f32_fp8(d.x, false);
    v2f t1 = __builtin_amdgcn_cvt_pk_f32_fp8(d.x, true);
    v2f t2 = __builtin_amdgcn_cvt_pk_f32_fp8(d.y, false);
    v2f t3 = __builtin_amdgcn_cvt_pk_f32_fp8(d.y, true);
    v2f t4 = __builtin_amdgcn_cvt_pk_f32_fp8(d.z, false);
    v2f t5 = __builtin_amdgcn_cvt_pk_f32_fp8(d.z, true);
    v2f t6 = __builtin_amdgcn_cvt_pk_f32_fp8(d.w, false);
    v2f t7 = __builtin_amdgcn_cvt_pk_f32_fp8(d.w, true);
    o.p0 = {t0.x, t0.y, t1.x};
    o.p1 = {t1.y, t2.x, t2.y};
    o.p2 = {t3.x, t3.y, t4.x};
    o.c  = {t4.y, t5.x, t5.y};
    o.n  = {t6.x, t6.y, t7.x};
    o.r  = t7.y;
}

__device__ __forceinline__ float compute_pair8(float4 R, float4 I, float w) {
    RecF rr, ii;
    decode_rec8(R, rr);
    decode_rec8(I, ii);
    V3 rp[3] = {rr.p0, rr.p1, rr.p2};
    V3 ip[3] = {ii.p0, ii.p1, ii.p2};
    return w * (cone_psi2(ip, rr.c, rr.n, rr.r) + cone_psi2(rp, ii.c, ii.n, ii.r));
}

// forced-issue 16-B load: result is a live asm output the allocator can't sink
__device__ __forceinline__ float4 gload16(const float4* p) {
    float4 r;
    asm volatile("global_load_dwordx4 %0, %1, off" : "=v"(r) : "v"(p));
    return r;
}
#define WAIT_VM(n) do { asm volatile("s_waitcnt vmcnt(" #n ")" ::: "memory"); \
                        __builtin_amdgcn_sched_barrier(0); } while (0)

// ---------------- phase 1: per-(batch,face) 16-B fp8 record ----------------
__global__ void precompute_tri_8(const float* __restrict__ verts,  // [B,V,3]
                                 const int*   __restrict__ faces,  // [F,3]
                                 float4* __restrict__ table,       // [B*F]
                                 float* __restrict__ out,          // [B]
                                 int V, int F, int B) {
    if (blockIdx.x == 0 && threadIdx.x < (unsigned)B)
        out[threadIdx.x] = 0.0f;

    const int b = blockIdx.x % B;      // batch -> XCD co-location with pair kernel
    const int chunk = blockIdx.x / B;
    const int f = chunk * blockDim.x + threadIdx.x;
    if (f >= F) return;

    const float* vb = verts + (size_t)b * (size_t)V * 3u;
    int i0 = faces[3 * f + 0];
    int i1 = faces[3 * f + 1];
    int i2 = faces[3 * f + 2];
    V3 v[3];
    v[0] = {vb[3 * i0 + 0], vb[3 * i0 + 1], vb[3 * i0 + 2]};
    v[1] = {vb[3 * i1 + 0], vb[3 * i1 + 1], vb[3 * i1 + 2]};
    v[2] = {vb[3 * i2 + 0], vb[3 * i2 + 1], vb[3 * i2 + 2]};
    V3 c, n; float r;
    tri_frame(v, c, n, r);
    int d0 = 0, d1 = 0, d2 = 0, d3 = 0;
    d0 = __builtin_amdgcn_cvt_pk_fp8_f32(v[0].x, v[0].y, d0, false);
    d0 = __builtin_amdgcn_cvt_pk_fp8_f32(v[0].z, v[1].x, d0, true);
    d1 = __builtin_amdgcn_cvt_pk_fp8_f32(v[1].y, v[1].z, d1, false);
    d1 = __builtin_amdgcn_cvt_pk_fp8_f32(v[2].x, v[2].y, d1, true);
    d2 = __builtin_amdgcn_cvt_pk_fp8_f32(v[2].z, c.x, d2, false);
    d2 = __builtin_amdgcn_cvt_pk_fp8_f32(c.y, c.z, d2, true);
    d3 = __builtin_amdgcn_cvt_pk_fp8_f32(n.x, n.y, d3, false);
    d3 = __builtin_amdgcn_cvt_pk_fp8_f32(n.z, r, d3, true);
    int4 rec = {d0, d1, d2, d3};
    table[(size_t)b * F + f] = *(float4*)&rec;
}

// ---------------- phase 2: asm-forced rolling pipeline, GPT=4 ----------------
// per group: issue next group's 4 loads -> vmcnt(4) -> compute current group.
__global__ void __launch_bounds__(256, 4)
pair_kernel_f8(const float4* __restrict__ table,  // [B*F]
               const int4*  __restrict__ coll4,   // [B*C4]
               float* __restrict__ out,           // [B]
               int F, int C4, int B) {
    const int b = blockIdx.x % B;                 // batch -> XCD pinning
    const int chunk = blockIdx.x / B;
    const int4* cb = coll4 + (size_t)b * C4;
    const float4* tb = table + (size_t)b * (size_t)F;
    const int base = chunk * (256 * 4) + (int)threadIdx.x;

    // all coll loads + weights resolved BEFORE the first asm gather, so the
    // compiler's automatic vmcnt waits drain here and don't touch the pipeline
    int g0 = base, g1 = base + 256, g2 = base + 512, g3 = base + 768;
    int4 q0 = (g0 < C4) ? cb[g0] : make_int4(-1, -1, -1, -1);
    int4 q1 = (g1 < C4) ? cb[g1] : make_int4(-1, -1, -1, -1);
    int4 q2 = (g2 < C4) ? cb[g2] : make_int4(-1, -1, -1, -1);
    int4 q3 = (g3 < C4) ? cb[g3] : make_int4(-1, -1, -1, -1);
    float w00 = ((q0.x | q0.y) >= 0) ? 1.0f : 0.0f;
    float w01 = ((q0.z | q0.w) >= 0) ? 1.0f : 0.0f;
    float w10 = ((q1.x | q1.y) >= 0) ? 1.0f : 0.0f;
    float w11 = ((q1.z | q1.w) >= 0) ? 1.0f : 0.0f;
    float w20 = ((q2.x | q2.y) >= 0) ? 1.0f : 0.0f;
    float w21 = ((q2.z | q2.w) >= 0) ? 1.0f : 0.0f;
    float w30 = ((q3.x | q3.y) >= 0) ? 1.0f : 0.0f;
    float w31 = ((q3.z | q3.w) >= 0) ? 1.0f : 0.0f;

    // prologue: group 0 in flight
    float4 A0 = gload16(tb + imax0(q0.x));
    float4 A1 = gload16(tb + imax0(q0.y));
    float4 A2 = gload16(tb + imax0(q0.z));
    float4 A3 = gload16(tb + imax0(q0.w));

    // i=0: issue group1, wait group0, compute group0
    float4 B0 = gload16(tb + imax0(q1.x));
    float4 B1 = gload16(tb + imax0(q1.y));
    float4 B2 = gload16(tb + imax0(q1.z));
    float4 B3 = gload16(tb + imax0(q1.w));
    WAIT_VM(4);
    float acc = compute_pair8(A0, A1, w00) + compute_pair8(A2, A3, w01);

    // i=1: issue group2, wait group1, compute group1
    A0 = gload16(tb + imax0(q2.x));
    A1 = gload16(tb + imax0(q2.y));
    A2 = gload16(tb + imax0(q2.z));
    A3 = gload16(tb + imax0(q2.w));
    WAIT_VM(4);
    acc += compute_pair8(B0, B1, w10) + compute_pair8(B2, B3, w11);

    // i=2: issue group3, wait group2, compute group2
    B0 = gload16(tb + imax0(q3.x));
    B1 = gload16(tb + imax0(q3.y));
    B2 = gload16(tb + imax0(q3.z));
    B3 = gload16(tb + imax0(q3.w));
    WAIT_VM(4);
    acc += compute_pair8(A0, A1, w20) + compute_pair8(A2, A3, w21);

    // i=3: wait group3, compute group3
    WAIT_VM(0);
    acc += compute_pair8(B0, B1, w30) + compute_pair8(B2, B3, w31);

    // wave (64) shuffle reduction
#pragma unroll
    for (int off = 32; off > 0; off >>= 1)
        acc += __shfl_down(acc, off, 64);

    __shared__ float red[4];
    int lane = threadIdx.x & 63;
    int wid  = threadIdx.x >> 6;
    if (lane == 0) red[wid] = acc;
    __syncthreads();
    if (threadIdx.x == 0) {
        float s = red[0] + red[1] + red[2] + red[3];
        atomicAdd(&out[b], s);
    }
}

// ---------------- fallback: direct gather (fp32 exact) ----------------
__global__ void interp_zero(float* out, int n) {
    int i = blockIdx.x * blockDim.x + threadIdx.x;
    if (i < n) out[i] = 0.0f;
}
__global__ void pair_kernel_gather(const float* __restrict__ verts,
                                   const int*   __restrict__ faces,
                                   const int2*  __restrict__ coll,
                                   float* __restrict__ out, int V, int C) {
    const int b = blockIdx.y;
    const float* vb = verts + (size_t)b * (size_t)V * 3u;
    const int2* cb = coll + (size_t)b * (size_t)C;
    float acc = 0.0f;
    const int stride = gridDim.x * blockDim.x;
    for (int c = blockIdx.x * blockDim.x + threadIdx.x; c < C; c += stride) {
        int2 idx = cb[c];
        if ((idx.x | idx.y) >= 0) {
            const int* fr = faces + 3 * idx.x;
            const int* fi = faces + 3 * idx.y;
            V3 tr[3], ti[3];
#pragma unroll
            for (int j = 0; j < 3; ++j) {
                int vr = fr[j];
                tr[j] = {vb[3 * vr + 0], vb[3 * vr + 1], vb[3 * vr + 2]};
                int vi = fi[j];
                ti[j] = {vb[3 * vi + 0], vb[3 * vi + 1], vb[3 * vi + 2]};
            }
            V3 rc, rn; float rr;
            tri_frame(tr, rc, rn, rr);
            V3 ic, in_; float ir;
            tri_frame(ti, ic, in_, ir);
            acc += cone_psi2(ti, rc, rn, rr);
            acc += cone_psi2(tr, ic, in_, ir);
        }
    }
#pragma unroll
    for (int off = 32; off > 0; off >>= 1)
        acc += __shfl_down(acc, off, 64);
    __shared__ float red[16];
    int lane = threadIdx.x & 63, wid = threadIdx.x >> 6;
    if (lane == 0) red[wid] = acc;
    __syncthreads();
    if (threadIdx.x == 0) {
        float s = 0.0f;
        int nw = blockDim.x >> 6;
        for (int i = 0; i < nw; ++i) s += red[i];
        atomicAdd(&out[b], s);
    }
}

extern "C" void kernel_launch(void* const* d_in, const int* in_sizes, int n_in,
                              void* d_out, int out_size, void* d_ws, size_t ws_size,
                              hipStream_t stream) {
    const float* verts = (const float*)d_in[0];
    const int*   faces = (const int*)d_in[1];
    float* out = (float*)d_out;

    const int B = out_size;                       // 8
    const int V = in_sizes[0] / (3 * B);          // 10475
    const int F = in_sizes[1] / 3;                // 20908
    const int C = in_sizes[2] / (2 * B);          // 262144

    const size_t table_bytes = (size_t)B * (size_t)F * 16u;
    const int per_block_pairs = 256 * 4 * 2;      // 2048 pairs per block

    if (ws_size >= table_bytes && (C % per_block_pairs) == 0) {
        float4* table = (float4*)d_ws;
        const int4* coll4 = (const int4*)d_in[2];
        const int C4 = C / 2;

        const int pchunks = (F + 255) / 256;
        precompute_tri_8<<<dim3(pchunks * B), dim3(256), 0, stream>>>(
            verts, faces, table, out, V, F, B);

        const int chunks = C / per_block_pairs;   // per batch: 128
        pair_kernel_f8<<<dim3(chunks * B), dim3(256), 0, stream>>>(
            table, coll4, out, F, C4, B);
    } else {
        interp_zero<<<1, 64, 0, stream>>>(out, B);
        pair_kernel_gather<<<dim3(256, B), dim3(256), 0, stream>>>(
            verts, faces, (const int2*)d_in[2], out, V, C);
    }
}